// Round 1
// baseline (684.667 us; speedup 1.0000x reference)
//
#include <hip/hip_runtime.h>
#include <math.h>

#define B 32
#define S 4096
#define H 1024
#define NCHUNK 32                         // pass-1 blocks per batch
#define ROWS_PER_BLOCK (S / NCHUNK)       // 128
#define ROWS_PER_WAVE (ROWS_PER_BLOCK/4)  // 32
#define PSTRIDE 1040                      // 1024 c + m + l, padded to 16B mult

// Pass 1: fused scores + online softmax + weighted context accumulation.
// One wave owns 32 contiguous s-rows; each lane holds 16 h-elements.
__global__ __launch_bounds__(256) void attn_pass1(
    const float* __restrict__ dec, const float* __restrict__ enc,
    float* __restrict__ scores, float* __restrict__ part)
{
    const int blk   = blockIdx.x;
    const int b     = blk / NCHUNK;
    const int chunk = blk % NCHUNK;
    const int lane  = threadIdx.x & 63;
    const int w     = threadIdx.x >> 6;

    const float4* dsp = (const float4*)(dec + (size_t)b * H);
    const float4 ds0 = dsp[lane];
    const float4 ds1 = dsp[lane + 64];
    const float4 ds2 = dsp[lane + 128];
    const float4 ds3 = dsp[lane + 192];

    float m = -INFINITY, l = 0.f;
    float4 a0 = {0.f,0.f,0.f,0.f}, a1 = a0, a2 = a0, a3 = a0;

    const int row0 = chunk * ROWS_PER_BLOCK + w * ROWS_PER_WAVE;
    for (int r = 0; r < ROWS_PER_WAVE; ++r) {
        const int row = row0 + r;
        const float4* ep = (const float4*)(enc + ((size_t)b * S + row) * H);
        const float4 e0 = ep[lane];
        const float4 e1 = ep[lane + 64];
        const float4 e2 = ep[lane + 128];
        const float4 e3 = ep[lane + 192];

        float p = 0.f;
        p = fmaf(e0.x, ds0.x, p); p = fmaf(e0.y, ds0.y, p);
        p = fmaf(e0.z, ds0.z, p); p = fmaf(e0.w, ds0.w, p);
        p = fmaf(e1.x, ds1.x, p); p = fmaf(e1.y, ds1.y, p);
        p = fmaf(e1.z, ds1.z, p); p = fmaf(e1.w, ds1.w, p);
        p = fmaf(e2.x, ds2.x, p); p = fmaf(e2.y, ds2.y, p);
        p = fmaf(e2.z, ds2.z, p); p = fmaf(e2.w, ds2.w, p);
        p = fmaf(e3.x, ds3.x, p); p = fmaf(e3.y, ds3.y, p);
        p = fmaf(e3.z, ds3.z, p); p = fmaf(e3.w, ds3.w, p);

        // 64-lane butterfly reduce (all lanes end with the full sum)
        p += __shfl_xor(p, 32);
        p += __shfl_xor(p, 16);
        p += __shfl_xor(p, 8);
        p += __shfl_xor(p, 4);
        p += __shfl_xor(p, 2);
        p += __shfl_xor(p, 1);
        const float score = p;

        if (lane == 0) scores[(size_t)b * S + row] = score;

        if (score > m) {               // wave-uniform branch (score uniform)
            const float alpha = __expf(m - score);   // exp(-inf)=0 on 1st iter
            m = score;
            l = fmaf(l, alpha, 1.f);
            a0.x = fmaf(a0.x, alpha, e0.x); a0.y = fmaf(a0.y, alpha, e0.y);
            a0.z = fmaf(a0.z, alpha, e0.z); a0.w = fmaf(a0.w, alpha, e0.w);
            a1.x = fmaf(a1.x, alpha, e1.x); a1.y = fmaf(a1.y, alpha, e1.y);
            a1.z = fmaf(a1.z, alpha, e1.z); a1.w = fmaf(a1.w, alpha, e1.w);
            a2.x = fmaf(a2.x, alpha, e2.x); a2.y = fmaf(a2.y, alpha, e2.y);
            a2.z = fmaf(a2.z, alpha, e2.z); a2.w = fmaf(a2.w, alpha, e2.w);
            a3.x = fmaf(a3.x, alpha, e3.x); a3.y = fmaf(a3.y, alpha, e3.y);
            a3.z = fmaf(a3.z, alpha, e3.z); a3.w = fmaf(a3.w, alpha, e3.w);
        } else {
            const float pe = __expf(score - m);
            l += pe;
            a0.x = fmaf(pe, e0.x, a0.x); a0.y = fmaf(pe, e0.y, a0.y);
            a0.z = fmaf(pe, e0.z, a0.z); a0.w = fmaf(pe, e0.w, a0.w);
            a1.x = fmaf(pe, e1.x, a1.x); a1.y = fmaf(pe, e1.y, a1.y);
            a1.z = fmaf(pe, e1.z, a1.z); a1.w = fmaf(pe, e1.w, a1.w);
            a2.x = fmaf(pe, e2.x, a2.x); a2.y = fmaf(pe, e2.y, a2.y);
            a2.z = fmaf(pe, e2.z, a2.z); a2.w = fmaf(pe, e2.w, a2.w);
            a3.x = fmaf(pe, e3.x, a3.x); a3.y = fmaf(pe, e3.y, a3.y);
            a3.z = fmaf(pe, e3.z, a3.z); a3.w = fmaf(pe, e3.w, a3.w);
        }
    }

    // Combine the 4 wave partials -> one block partial
    __shared__ float sm[4], sl[4];
    __shared__ float sc[4][1024];
    if (lane == 0) { sm[w] = m; sl[w] = l; }
    *(float4*)&sc[w][lane * 4]       = a0;
    *(float4*)&sc[w][lane * 4 + 256] = a1;
    *(float4*)&sc[w][lane * 4 + 512] = a2;
    *(float4*)&sc[w][lane * 4 + 768] = a3;
    __syncthreads();

    const float M  = fmaxf(fmaxf(sm[0], sm[1]), fmaxf(sm[2], sm[3]));
    const float al0 = __expf(sm[0] - M), al1 = __expf(sm[1] - M);
    const float al2 = __expf(sm[2] - M), al3 = __expf(sm[3] - M);
    const float Lb = sl[0]*al0 + sl[1]*al1 + sl[2]*al2 + sl[3]*al3;

    const int t = threadIdx.x;
    const float4 c0 = *(const float4*)&sc[0][t * 4];
    const float4 c1 = *(const float4*)&sc[1][t * 4];
    const float4 c2 = *(const float4*)&sc[2][t * 4];
    const float4 c3 = *(const float4*)&sc[3][t * 4];
    float4 cp;
    cp.x = c0.x*al0 + c1.x*al1 + c2.x*al2 + c3.x*al3;
    cp.y = c0.y*al0 + c1.y*al1 + c2.y*al2 + c3.y*al3;
    cp.z = c0.z*al0 + c1.z*al1 + c2.z*al2 + c3.z*al3;
    cp.w = c0.w*al0 + c1.w*al1 + c2.w*al2 + c3.w*al3;

    float* pb = part + (size_t)blk * PSTRIDE;
    *(float4*)&pb[t * 4] = cp;
    if (t == 0) { pb[1024] = M; pb[1025] = Lb; }
}

// Pass 2: reduce the 32 per-block partials of each batch to global (M, L),
// then emit context (h-slice) and attn (s-slice).
__global__ __launch_bounds__(256) void attn_pass2(
    const float* __restrict__ scores, const float* __restrict__ part,
    float* __restrict__ out)
{
    const int b = blockIdx.x >> 2;
    const int j = blockIdx.x & 3;
    const int t = threadIdx.x;
    const float* pbase = part + (size_t)b * NCHUNK * PSTRIDE;

    float M = -INFINITY;
    for (int i = 0; i < NCHUNK; ++i)
        M = fmaxf(M, pbase[i * PSTRIDE + 1024]);
    float L = 0.f;
    for (int i = 0; i < NCHUNK; ++i)
        L += pbase[i * PSTRIDE + 1025] * __expf(pbase[i * PSTRIDE + 1024] - M);
    const float invL = 1.f / L;

    // context slice: h = j*256 + t
    const int h = j * 256 + t;
    float acc = 0.f;
    for (int i = 0; i < NCHUNK; ++i)
        acc = fmaf(__expf(pbase[i * PSTRIDE + 1024] - M),
                   pbase[i * PSTRIDE + h], acc);
    out[(size_t)b * H + h] = acc * invL;

    // attn slice: s in [j*1024, (j+1)*1024)
    float* attn_out = out + (size_t)B * H;
    for (int k = 0; k < 4; ++k) {
        const int s = j * 1024 + k * 256 + t;
        attn_out[(size_t)b * S + s] =
            __expf(scores[(size_t)b * S + s] - M) * invL;
    }
}

extern "C" void kernel_launch(void* const* d_in, const int* in_sizes, int n_in,
                              void* d_out, int out_size, void* d_ws, size_t ws_size,
                              hipStream_t stream) {
    const float* dec = (const float*)d_in[0];   // (32, 1024)
    const float* enc = (const float*)d_in[1];   // (32, 4096, 1024)
    float* out = (float*)d_out;                 // context(32*1024) ++ attn(32*4096)
    float* ws  = (float*)d_ws;
    float* scores = ws;                         // B*S floats
    float* part   = ws + (size_t)B * S;         // B*NCHUNK*PSTRIDE floats (~4.3 MB)

    attn_pass1<<<B * NCHUNK, 256, 0, stream>>>(dec, enc, scores, part);
    attn_pass2<<<B * 4, 256, 0, stream>>>(scores, part, out);
}